// Round 2
// baseline (32.280 us; speedup 1.0000x reference)
//
#include <hip/hip_runtime.h>

typedef float float4v __attribute__((ext_vector_type(4)));

#define BLOCK 256
#define UNROLL 8

// ---- tiny not-a-knot spline solve (tridiagonal -> Thomas), n = 10 ----
// Writes expanded x-basis coefficients {a3,a2,a1,a0} for 9 intervals into sc,
// knots into sp. Called by thread 0 of each block.
__device__ __forceinline__ void spline_setup(const float* __restrict__ points,
                                             const float* __restrict__ values,
                                             float4* sc, float* sp)
{
    float p[10], v[10];
#pragma unroll
    for (int k = 0; k < 10; ++k) { p[k] = points[k]; v[k] = values[k]; }
    float dx[9], sl[9];
#pragma unroll
    for (int k = 0; k < 9; ++k) { dx[k] = p[k + 1] - p[k]; sl[k] = (v[k + 1] - v[k]) / dx[k]; }

    float dg[10], lo[10], up[10], bb[10];
    float d0 = p[2] - p[0];
    dg[0] = dx[1]; up[0] = d0; lo[0] = 0.0f;
    bb[0] = ((dx[0] + 2.0f * d0) * dx[1] * sl[0] + dx[0] * dx[0] * sl[1]) / d0;
#pragma unroll
    for (int i = 1; i <= 8; ++i) {
        lo[i] = dx[i];
        dg[i] = 2.0f * (dx[i - 1] + dx[i]);
        up[i] = dx[i - 1];
        bb[i] = 3.0f * (dx[i] * sl[i - 1] + dx[i - 1] * sl[i]);
    }
    float dn = p[9] - p[7];
    lo[9] = dn; dg[9] = dx[7]; up[9] = 0.0f;
    bb[9] = (dx[8] * dx[8] * sl[7] + (2.0f * dn + dx[8]) * dx[7] * sl[8]) / dn;

    float cp[10], bp[10];
    cp[0] = up[0] / dg[0];
    bp[0] = bb[0] / dg[0];
#pragma unroll
    for (int i = 1; i <= 9; ++i) {
        float m = dg[i] - lo[i] * cp[i - 1];
        cp[i] = up[i] / m;
        bp[i] = (bb[i] - lo[i] * bp[i - 1]) / m;
    }
    float s[10];
    s[9] = bp[9];
#pragma unroll
    for (int i = 8; i >= 0; --i) s[i] = bp[i] - cp[i] * s[i + 1];

#pragma unroll
    for (int i = 0; i < 9; ++i) {
        float tt = (s[i] + s[i + 1] - 2.0f * sl[i]) / dx[i];
        float c3 = tt / dx[i];
        float c2 = (sl[i] - s[i]) / dx[i] - tt;
        float c1 = s[i];
        float c0 = v[i];
        float pi = p[i];
        float a3 = c3;
        float a2 = c2 - 3.0f * c3 * pi;
        float a1 = (3.0f * c3 * pi - 2.0f * c2) * pi + c1;
        float a0 = ((-c3 * pi + c2) * pi - c1) * pi + c0;
        sc[i] = make_float4(a3, a2, a1, a0);
    }
#pragma unroll
    for (int k = 0; k < 10; ++k) sp[k] = p[k];
}

// Fast path: total == gridDim.x * BLOCK * UNROLL * 4 exactly.
// All UNROLL strided float4 loads issued BEFORE the setup barrier (MLP=8,
// overlaps thread0's solve), then compute + store.
__global__ __launch_bounds__(BLOCK) void spline_eval_fast(
    const float* __restrict__ xin,
    const float* __restrict__ points,
    const float* __restrict__ values,
    float* __restrict__ out)
{
    __shared__ float4 sc[9];
    __shared__ float sp[10];

    const float4v* __restrict__ x4 = (const float4v*)xin;
    float4v* __restrict__ o4 = (float4v*)out;

    const int stride = gridDim.x * BLOCK;
    const int tid = blockIdx.x * BLOCK + threadIdx.x;

    float4v xv[UNROLL];
#pragma unroll
    for (int k = 0; k < UNROLL; ++k) xv[k] = x4[tid + k * stride];

    if (threadIdx.x == 0) spline_setup(points, values, sc, sp);
    __syncthreads();

    const float q1 = sp[1], q2 = sp[2], q3 = sp[3], q4 = sp[4];
    const float q5 = sp[5], q6 = sp[6], q7 = sp[7], q8 = sp[8];

#pragma unroll
    for (int k = 0; k < UNROLL; ++k) {
        float4v yv;
#pragma unroll
        for (int j = 0; j < 4; ++j) {
            float xx = xv[k][j];
            int i = (xx >= q1) + (xx >= q2) + (xx >= q3) + (xx >= q4) +
                    (xx >= q5) + (xx >= q6) + (xx >= q7) + (xx >= q8);
            float4 c = sc[i];
            yv[j] = ((c.x * xx + c.y) * xx + c.z) * xx + c.w;
        }
        o4[tid + k * stride] = yv;
    }
}

// Generic fallback: grid-stride float4 loop + scalar tail.
__global__ __launch_bounds__(BLOCK) void spline_eval_generic(
    const float* __restrict__ xin,
    const float* __restrict__ points,
    const float* __restrict__ values,
    float* __restrict__ out,
    int n4, int total)
{
    __shared__ float4 sc[9];
    __shared__ float sp[10];

    if (threadIdx.x == 0) spline_setup(points, values, sc, sp);
    __syncthreads();

    const float q1 = sp[1], q2 = sp[2], q3 = sp[3], q4 = sp[4];
    const float q5 = sp[5], q6 = sp[6], q7 = sp[7], q8 = sp[8];

    const float4v* __restrict__ x4 = (const float4v*)xin;
    float4v* __restrict__ o4 = (float4v*)out;

    int idx = blockIdx.x * blockDim.x + threadIdx.x;
    int stride = gridDim.x * blockDim.x;

    for (int vi = idx; vi < n4; vi += stride) {
        float4v xv = x4[vi];
        float4v yv;
#pragma unroll
        for (int j = 0; j < 4; ++j) {
            float xx = xv[j];
            int i = (xx >= q1) + (xx >= q2) + (xx >= q3) + (xx >= q4) +
                    (xx >= q5) + (xx >= q6) + (xx >= q7) + (xx >= q8);
            float4 c = sc[i];
            yv[j] = ((c.x * xx + c.y) * xx + c.z) * xx + c.w;
        }
        o4[vi] = yv;
    }

    int tail = n4 * 4;
    if (blockIdx.x == 0) {
        for (int e = tail + threadIdx.x; e < total; e += blockDim.x) {
            float xx = xin[e];
            int i = (xx >= q1) + (xx >= q2) + (xx >= q3) + (xx >= q4) +
                    (xx >= q5) + (xx >= q6) + (xx >= q7) + (xx >= q8);
            float4 c = sc[i];
            out[e] = ((c.x * xx + c.y) * xx + c.z) * xx + c.w;
        }
    }
}

extern "C" void kernel_launch(void* const* d_in, const int* in_sizes, int n_in,
                              void* d_out, int out_size, void* d_ws, size_t ws_size,
                              hipStream_t stream) {
    const float* x = (const float*)d_in[0];
    const float* points = (const float*)d_in[1];
    const float* values = (const float*)d_in[2];
    float* out = (float*)d_out;

    int total = out_size;               // 4096*4096 = 16777216
    const int per_block = BLOCK * UNROLL * 4;   // elements per block, fast path

    if (total % per_block == 0) {
        int grid = total / per_block;   // 2048 for 4096^2
        spline_eval_fast<<<grid, BLOCK, 0, stream>>>(x, points, values, out);
    } else {
        int n4 = total / 4;
        int grid = 2048;
        spline_eval_generic<<<grid, BLOCK, 0, stream>>>(x, points, values, out, n4, total);
    }
}

// Round 3
// 27.709 us; speedup vs baseline: 1.1650x; 1.1650x over previous
//
#include <hip/hip_runtime.h>

typedef float float4v __attribute__((ext_vector_type(4)));

#define BLOCK 256

// ---- tiny not-a-knot spline solve (tridiagonal -> Thomas), n = 10 ----
// Writes expanded x-basis coefficients into SoA float2 tables:
//   s32[i] = {a3, a2},  s10[i] = {a1, a0}
// so each 8B entry owns a distinct LDS bank pair (9 entries -> 18 banks):
// gathers by per-lane interval index are conflict-free by construction.
__device__ __forceinline__ void spline_setup(const float* __restrict__ points,
                                             const float* __restrict__ values,
                                             float2* s32, float2* s10, float* sp)
{
    float p[10], v[10];
#pragma unroll
    for (int k = 0; k < 10; ++k) { p[k] = points[k]; v[k] = values[k]; }
    float dx[9], sl[9];
#pragma unroll
    for (int k = 0; k < 9; ++k) { dx[k] = p[k + 1] - p[k]; sl[k] = (v[k + 1] - v[k]) / dx[k]; }

    float dg[10], lo[10], up[10], bb[10];
    float d0 = p[2] - p[0];
    dg[0] = dx[1]; up[0] = d0; lo[0] = 0.0f;
    bb[0] = ((dx[0] + 2.0f * d0) * dx[1] * sl[0] + dx[0] * dx[0] * sl[1]) / d0;
#pragma unroll
    for (int i = 1; i <= 8; ++i) {
        lo[i] = dx[i];
        dg[i] = 2.0f * (dx[i - 1] + dx[i]);
        up[i] = dx[i - 1];
        bb[i] = 3.0f * (dx[i] * sl[i - 1] + dx[i - 1] * sl[i]);
    }
    float dn = p[9] - p[7];
    lo[9] = dn; dg[9] = dx[7]; up[9] = 0.0f;
    bb[9] = (dx[8] * dx[8] * sl[7] + (2.0f * dn + dx[8]) * dx[7] * sl[8]) / dn;

    float cp[10], bp[10];
    cp[0] = up[0] / dg[0];
    bp[0] = bb[0] / dg[0];
#pragma unroll
    for (int i = 1; i <= 9; ++i) {
        float m = dg[i] - lo[i] * cp[i - 1];
        cp[i] = up[i] / m;
        bp[i] = (bb[i] - lo[i] * bp[i - 1]) / m;
    }
    float s[10];
    s[9] = bp[9];
#pragma unroll
    for (int i = 8; i >= 0; --i) s[i] = bp[i] - cp[i] * s[i + 1];

#pragma unroll
    for (int i = 0; i < 9; ++i) {
        float tt = (s[i] + s[i + 1] - 2.0f * sl[i]) / dx[i];
        float c3 = tt / dx[i];
        float c2 = (sl[i] - s[i]) / dx[i] - tt;
        float c1 = s[i];
        float c0 = v[i];
        float pi = p[i];
        float a3 = c3;
        float a2 = c2 - 3.0f * c3 * pi;
        float a1 = (3.0f * c3 * pi - 2.0f * c2) * pi + c1;
        float a0 = ((-c3 * pi + c2) * pi - c1) * pi + c0;
        s32[i] = make_float2(a3, a2);
        s10[i] = make_float2(a1, a0);
    }
#pragma unroll
    for (int k = 0; k < 10; ++k) sp[k] = p[k];
}

// R1 loop structure (grid-stride float4), conflict-free SoA LDS gather.
__global__ __launch_bounds__(BLOCK) void spline_eval_kernel(
    const float* __restrict__ xin,
    const float* __restrict__ points,
    const float* __restrict__ values,
    float* __restrict__ out,
    int n4, int total)
{
    __shared__ float2 s32[9];   // {a3,a2}  — banks 2i, 2i+1
    __shared__ float2 s10[9];   // {a1,a0}  — banks 18+2i, 19+2i (mod 32)
    __shared__ float sp[10];

    if (threadIdx.x == 0) spline_setup(points, values, s32, s10, sp);
    __syncthreads();

    const float q1 = sp[1], q2 = sp[2], q3 = sp[3], q4 = sp[4];
    const float q5 = sp[5], q6 = sp[6], q7 = sp[7], q8 = sp[8];

    const float4v* __restrict__ x4 = (const float4v*)xin;
    float4v* __restrict__ o4 = (float4v*)out;

    int idx = blockIdx.x * blockDim.x + threadIdx.x;
    int stride = gridDim.x * blockDim.x;

    for (int vi = idx; vi < n4; vi += stride) {
        float4v xv = x4[vi];
        float4v yv;
#pragma unroll
        for (int j = 0; j < 4; ++j) {
            float xx = xv[j];
            int i = (xx >= q1) + (xx >= q2) + (xx >= q3) + (xx >= q4) +
                    (xx >= q5) + (xx >= q6) + (xx >= q7) + (xx >= q8);
            float2 h = s32[i];
            float2 l = s10[i];
            yv[j] = ((h.x * xx + h.y) * xx + l.x) * xx + l.y;
        }
        o4[vi] = yv;
    }

    // scalar tail (total not divisible by 4) — handled by block 0
    int tail = n4 * 4;
    if (blockIdx.x == 0) {
        for (int e = tail + threadIdx.x; e < total; e += blockDim.x) {
            float xx = xin[e];
            int i = (xx >= q1) + (xx >= q2) + (xx >= q3) + (xx >= q4) +
                    (xx >= q5) + (xx >= q6) + (xx >= q7) + (xx >= q8);
            float2 h = s32[i];
            float2 l = s10[i];
            out[e] = ((h.x * xx + h.y) * xx + l.x) * xx + l.y;
        }
    }
}

extern "C" void kernel_launch(void* const* d_in, const int* in_sizes, int n_in,
                              void* d_out, int out_size, void* d_ws, size_t ws_size,
                              hipStream_t stream) {
    const float* x = (const float*)d_in[0];
    const float* points = (const float*)d_in[1];
    const float* values = (const float*)d_in[2];
    float* out = (float*)d_out;

    int total = out_size;          // 4096*4096 = 16777216
    int n4 = total / 4;            // float4 elements

    const int block = BLOCK;
    const int grid = 2048;         // 8 blocks/CU co-resident, grid-stride x8

    spline_eval_kernel<<<grid, block, 0, stream>>>(x, points, values, out, n4, total);
}